// Round 1
// baseline (101.474 us; speedup 1.0000x reference)
//
#include <hip/hip_runtime.h>
#include <stdint.h>

typedef float  f32x4  __attribute__((ext_vector_type(4)));
typedef short  bf16x8 __attribute__((ext_vector_type(8)));
typedef int    i32x4  __attribute__((ext_vector_type(4)));
typedef unsigned int u32x2 __attribute__((ext_vector_type(2)));

#define C1f 0.70710678118654752f
#define C2f 0.5f
#define C3f 0.35355339059327373f

#define RPB 32          // rows per block
#define RB  1040        // LDS row stride bytes (512*2 + 16 pad; /4 == 260 == 4 mod 32)
#define NT  256

__device__ __forceinline__ unsigned int f2b(float f) {
    unsigned int u; __builtin_memcpy(&u, &f, 4);
    u += 0x7fffu + ((u >> 16) & 1u);          // RTNE f32 -> bf16
    return u >> 16;
}
__device__ __forceinline__ float b2f(unsigned int b) {
    unsigned int u = b << 16; float f; __builtin_memcpy(&f, &u, 4); return f;
}
__device__ __forceinline__ unsigned int pack2(float lo, float hi) {
    return f2b(lo) | (f2b(hi) << 16);
}
__device__ __forceinline__ bf16x8 cast8(i32x4 v) {
    bf16x8 r; __builtin_memcpy(&r, &v, 16); return r;
}

template<int USE_WS>
__global__ __launch_bounds__(NT, 4)
void wavelet_mlp(const float* __restrict__ x,
                 const float* __restrict__ W0, const float* __restrict__ b0,
                 const float* __restrict__ W1, const float* __restrict__ b1,
                 const float* __restrict__ W2, const float* __restrict__ b2,
                 const float* __restrict__ Wa, const float* __restrict__ ba,
                 const unsigned short* __restrict__ wsb,
                 float* __restrict__ out)
{
    __shared__ char lds[RPB * RB];

    const int tid  = threadIdx.x;
    const int lane = tid & 63;
    const int wave = tid >> 6;
    const long rowblk = (long)blockIdx.x * RPB;

    // ---------- stage 1: load x, forward 3-level wavelet (fully thread-local), bf16 -> LDS ----------
    #pragma unroll
    for (int it = 0; it < 4; ++it) {
        const int slot = tid + it * NT;       // 0..1023 = 32 rows * 32 segs
        const int r = slot >> 5, seg = slot & 31;
        const float4* xp = (const float4*)(x + (rowblk + r) * 512 + seg * 16);
        float4 v[4];
        v[0] = xp[0]; v[1] = xp[1]; v[2] = xp[2]; v[3] = xp[3];
        const float* xa = (const float*)v;
        float d0[8], a1[8];
        #pragma unroll
        for (int p = 0; p < 8; ++p) { d0[p] = (xa[2*p] - xa[2*p+1]) * C1f; a1[p] = (xa[2*p] + xa[2*p+1]) * C1f; }
        float d1[4], a2[4];
        #pragma unroll
        for (int p = 0; p < 4; ++p) { d1[p] = (a1[2*p] - a1[2*p+1]) * C1f; a2[p] = (a1[2*p] + a1[2*p+1]) * C1f; }
        float d2[2], a3[2];
        #pragma unroll
        for (int p = 0; p < 2; ++p) { d2[p] = (a2[2*p] - a2[2*p+1]) * C1f; a3[p] = (a2[2*p] + a2[2*p+1]) * C1f; }

        char* rb = lds + r * RB;
        i32x4 pd0 = { (int)pack2(d0[0],d0[1]), (int)pack2(d0[2],d0[3]),
                      (int)pack2(d0[4],d0[5]), (int)pack2(d0[6],d0[7]) };
        *(i32x4*)(rb + seg*16) = pd0;                         // d0[8seg..8seg+7]
        u32x2 pd1 = { pack2(d1[0],d1[1]), pack2(d1[2],d1[3]) };
        *(u32x2*)(rb + 512 + seg*8) = pd1;                    // d1[4seg..4seg+3]
        *(unsigned int*)(rb + 768 + seg*4) = pack2(d2[0],d2[1]); // d2[2seg..2seg+1]
        *(unsigned int*)(rb + 896 + seg*4) = pack2(a3[0],a3[1]); // a3[2seg..2seg+1]
    }
    __syncthreads();

    // A fragment: lane holds A[m = lane&15][k = (lane>>4)*8 + e], m89-verified family layout
    auto ldA = [&](int roff, int mtile, int ks) -> bf16x8 {
        const char* p = lds + (mtile*16 + (lane & 15)) * RB + roff + ks*64 + ((lane >> 4) * 16);
        return cast8(*(const i32x4*)p);
    };
    // B fragment: lane holds B[k][n = lane&15] = W[n][k], k = ks*32 + (lane>>4)*8 + e (8 contiguous)
    auto ldB = [&](const float* Wf, const unsigned short* Wb, int K, int ntile, int ks) -> bf16x8 {
        const int row = ntile*16 + (lane & 15);
        const int k   = ks*32 + ((lane >> 4) * 8);
        if (USE_WS) {
            return cast8(*(const i32x4*)(Wb + (size_t)row * K + k));
        } else {
            const float4* p = (const float4*)(Wf + (size_t)row * K + k);
            float4 u0 = p[0], u1 = p[1];
            i32x4 v = { (int)pack2(u0.x,u0.y), (int)pack2(u0.z,u0.w),
                        (int)pack2(u1.x,u1.y), (int)pack2(u1.z,u1.w) };
            return cast8(v);
        }
    };
    // C store: col = lane&15, row = (lane>>4)*4 + i  (m89/m91 verified)
    auto stC = [&](int roff, int mtile, int col, f32x4 acc, const float* bias) {
        const float bv = bias[col];
        const int r0 = mtile*16 + ((lane >> 4) << 2);
        char* base = lds + roff + col*2;
        #pragma unroll
        for (int i2 = 0; i2 < 4; ++i2)
            *(unsigned short*)(base + (size_t)(r0 + i2) * RB) = (unsigned short)f2b(acc[i2] + bv);
    };

    // ---------- GEMM0: y_d0[32x256] = d0[32x256] @ W0^T ----------
    {
        f32x4 acc[2][4] = {};
        #pragma unroll
        for (int ks = 0; ks < 8; ++ks) {
            bf16x8 aA = ldA(0, 0, ks);
            bf16x8 aB = ldA(0, 1, ks);
            #pragma unroll
            for (int n = 0; n < 4; ++n) {
                bf16x8 b = ldB(W0, wsb, 256, wave*4 + n, ks);
                acc[0][n] = __builtin_amdgcn_mfma_f32_16x16x32_bf16(aA, b, acc[0][n], 0, 0, 0);
                acc[1][n] = __builtin_amdgcn_mfma_f32_16x16x32_bf16(aB, b, acc[1][n], 0, 0, 0);
            }
        }
        __syncthreads();   // all d0 A-reads done before y0 overwrites bytes 0..511
        #pragma unroll
        for (int m = 0; m < 2; ++m)
            #pragma unroll
            for (int n = 0; n < 4; ++n)
                stC(0, m, (wave*4 + n)*16 + (lane & 15), acc[m][n], b0);
    }

    // ---------- GEMM1: y_d1[32x128] = d1 @ W1^T ----------
    {
        f32x4 acc[2][2] = {};
        #pragma unroll
        for (int ks = 0; ks < 4; ++ks) {
            bf16x8 aA = ldA(512, 0, ks);
            bf16x8 aB = ldA(512, 1, ks);
            #pragma unroll
            for (int n = 0; n < 2; ++n) {
                bf16x8 b = ldB(W1, wsb + 65536, 128, wave*2 + n, ks);
                acc[0][n] = __builtin_amdgcn_mfma_f32_16x16x32_bf16(aA, b, acc[0][n], 0, 0, 0);
                acc[1][n] = __builtin_amdgcn_mfma_f32_16x16x32_bf16(aB, b, acc[1][n], 0, 0, 0);
            }
        }
        __syncthreads();
        #pragma unroll
        for (int m = 0; m < 2; ++m)
            #pragma unroll
            for (int n = 0; n < 2; ++n)
                stC(512, m, (wave*2 + n)*16 + (lane & 15), acc[m][n], b1);
    }

    // ---------- GEMM2 + GEMMa: y_d2 = d2 @ W2^T, y_a = a3 @ Wa^T ----------
    {
        f32x4 acc2[2] = {}, acca[2] = {};
        #pragma unroll
        for (int ks = 0; ks < 2; ++ks) {
            bf16x8 aA2 = ldA(768, 0, ks);
            bf16x8 aB2 = ldA(768, 1, ks);
            bf16x8 b2f_ = ldB(W2, wsb + 81920, 64, wave, ks);
            acc2[0] = __builtin_amdgcn_mfma_f32_16x16x32_bf16(aA2, b2f_, acc2[0], 0, 0, 0);
            acc2[1] = __builtin_amdgcn_mfma_f32_16x16x32_bf16(aB2, b2f_, acc2[1], 0, 0, 0);
            bf16x8 aAa = ldA(896, 0, ks);
            bf16x8 aBa = ldA(896, 1, ks);
            bf16x8 baf = ldB(Wa, wsb + 86016, 64, wave, ks);
            acca[0] = __builtin_amdgcn_mfma_f32_16x16x32_bf16(aAa, baf, acca[0], 0, 0, 0);
            acca[1] = __builtin_amdgcn_mfma_f32_16x16x32_bf16(aBa, baf, acca[1], 0, 0, 0);
        }
        __syncthreads();
        #pragma unroll
        for (int m = 0; m < 2; ++m) {
            stC(768, m, wave*16 + (lane & 15), acc2[m], b2);
            stC(896, m, wave*16 + (lane & 15), acca[m], ba);
        }
    }
    __syncthreads();

    // ---------- epilogue: inverse wavelet gather + store ----------
    // out[j] = C3*ya[j>>3] +- C3*yd2[j>>3] +- C2*yd1[j>>2] +- C1*yd0[j>>1]
    #pragma unroll
    for (int it = 0; it < 4; ++it) {
        const int slot = tid + it * NT;
        const int r = slot >> 5, seg = slot & 31;
        const char* yb = lds + r * RB;
        i32x4 p0 = *(const i32x4*)(yb + seg*16);
        u32x2 p1 = *(const u32x2*)(yb + 512 + seg*8);
        unsigned int p2 = *(const unsigned int*)(yb + 768 + seg*4);
        unsigned int pa = *(const unsigned int*)(yb + 896 + seg*4);
        float yd0[8], yd1[4], yd2[2], ya[2];
        #pragma unroll
        for (int i2 = 0; i2 < 4; ++i2) {
            unsigned int w = (unsigned int)p0[i2];
            yd0[2*i2]   = b2f(w & 0xffffu);
            yd0[2*i2+1] = b2f(w >> 16);
        }
        yd1[0] = b2f(p1[0] & 0xffffu); yd1[1] = b2f(p1[0] >> 16);
        yd1[2] = b2f(p1[1] & 0xffffu); yd1[3] = b2f(p1[1] >> 16);
        yd2[0] = b2f(p2 & 0xffffu);    yd2[1] = b2f(p2 >> 16);
        ya[0]  = b2f(pa & 0xffffu);    ya[1]  = b2f(pa >> 16);

        float o[16];
        #pragma unroll
        for (int jj = 0; jj < 16; ++jj) {
            const float s0 = (jj & 1)        ? -C1f : C1f;
            const float s1 = ((jj >> 1) & 1) ? -C2f : C2f;
            const float s2 = ((jj >> 2) & 1) ? -C3f : C3f;
            o[jj] = C3f * ya[jj >> 3] + s2 * yd2[jj >> 3] + s1 * yd1[jj >> 2] + s0 * yd0[jj >> 1];
        }
        float4* op = (float4*)(out + (rowblk + r) * 512 + seg * 16);
        const float4* ov = (const float4*)o;
        op[0] = ov[0]; op[1] = ov[1]; op[2] = ov[2]; op[3] = ov[3];
    }
}

// convert all weights to bf16 into workspace (runs every call; deterministic)
__global__ void conv_weights(const float* __restrict__ W0, const float* __restrict__ W1,
                             const float* __restrict__ W2, const float* __restrict__ Wa,
                             unsigned short* __restrict__ ws)
{
    const int i = blockIdx.x * 256 + threadIdx.x;
    if (i < 65536)        ws[i] = (unsigned short)f2b(W0[i]);
    else if (i < 81920)   ws[i] = (unsigned short)f2b(W1[i - 65536]);
    else if (i < 86016)   ws[i] = (unsigned short)f2b(W2[i - 81920]);
    else if (i < 90112)   ws[i] = (unsigned short)f2b(Wa[i - 86016]);
}

extern "C" void kernel_launch(void* const* d_in, const int* in_sizes, int n_in,
                              void* d_out, int out_size, void* d_ws, size_t ws_size,
                              hipStream_t stream)
{
    const float* x  = (const float*)d_in[0];
    const float* W0 = (const float*)d_in[1];
    const float* b0 = (const float*)d_in[2];
    const float* W1 = (const float*)d_in[3];
    const float* b1 = (const float*)d_in[4];
    const float* W2 = (const float*)d_in[5];
    const float* b2 = (const float*)d_in[6];
    const float* Wa = (const float*)d_in[7];
    const float* ba = (const float*)d_in[8];
    float* out = (float*)d_out;

    const int nrows = in_sizes[0] / 512;      // 65536
    const int nblk  = nrows / RPB;            // 2048

    if (ws_size >= (size_t)90112 * sizeof(unsigned short)) {
        unsigned short* ws = (unsigned short*)d_ws;
        conv_weights<<<352, 256, 0, stream>>>(W0, W1, W2, Wa, ws);
        wavelet_mlp<1><<<nblk, NT, 0, stream>>>(x, W0, b0, W1, b1, W2, b2, Wa, ba, ws, out);
    } else {
        wavelet_mlp<0><<<nblk, NT, 0, stream>>>(x, W0, b0, W1, b1, W2, b2, Wa, ba, nullptr, out);
    }
}

// Round 2
// 96.995 us; speedup vs baseline: 1.0462x; 1.0462x over previous
//
#include <hip/hip_runtime.h>
#include <stdint.h>

typedef float  f32x4  __attribute__((ext_vector_type(4)));
typedef short  bf16x8 __attribute__((ext_vector_type(8)));
typedef int    i32x4  __attribute__((ext_vector_type(4)));
typedef unsigned int u32x2 __attribute__((ext_vector_type(2)));

#define C1f 0.70710678118654752f
#define C2f 0.5f
#define C3f 0.35355339059327373f

#define RPB 32          // rows per block
#define RB  1040        // LDS row stride bytes (512*2 + 16 pad; /4 == 260 == 4 mod 32)
#define NT  256

__device__ __forceinline__ unsigned int f2b(float f) {
    unsigned int u; __builtin_memcpy(&u, &f, 4);
    u += 0x7fffu + ((u >> 16) & 1u);          // RTNE f32 -> bf16
    return u >> 16;
}
__device__ __forceinline__ float b2f(unsigned int b) {
    unsigned int u = b << 16; float f; __builtin_memcpy(&f, &u, 4); return f;
}
__device__ __forceinline__ unsigned int pack2(float lo, float hi) {
    return f2b(lo) | (f2b(hi) << 16);
}
__device__ __forceinline__ bf16x8 cast8(i32x4 v) {
    bf16x8 r; __builtin_memcpy(&r, &v, 16); return r;
}

template<int USE_WS>
__global__ __launch_bounds__(NT, 4)
void wavelet_mlp(const float* __restrict__ x,
                 const float* __restrict__ W0, const float* __restrict__ b0,
                 const float* __restrict__ W1, const float* __restrict__ b1,
                 const float* __restrict__ W2, const float* __restrict__ b2,
                 const float* __restrict__ Wa, const float* __restrict__ ba,
                 const unsigned short* __restrict__ wsb,
                 float* __restrict__ out)
{
    __shared__ char lds[RPB * RB];

    const int tid  = threadIdx.x;
    const int lane = tid & 63;
    const int wave = tid >> 6;
    const long rowblk = (long)blockIdx.x * RPB;

    // B fragment: lane holds B[k][n = lane&15] = W[n][k], k = ks*32 + (lane>>4)*8 (+e, 8 contiguous)
    auto ldB = [&](const float* Wf, const unsigned short* Wb, int K, int ntile, int ks) -> bf16x8 {
        const int row = ntile*16 + (lane & 15);
        const int k   = ks*32 + ((lane >> 4) * 8);
        if (USE_WS) {
            return cast8(*(const i32x4*)(Wb + (size_t)row * K + k));
        } else {
            const float4* p = (const float4*)(Wf + (size_t)row * K + k);
            float4 u0 = p[0], u1 = p[1];
            i32x4 v = { (int)pack2(u0.x,u0.y), (int)pack2(u0.z,u0.w),
                        (int)pack2(u1.x,u1.y), (int)pack2(u1.z,u1.w) };
            return cast8(v);
        }
    };

    // ---- prefetch (pre-barrier, no LDS dependence): x, biases, GEMM0 B ks=0,1 ----
    float4 v[16];
    #pragma unroll
    for (int it = 0; it < 4; ++it) {
        const int slot = tid + it * NT;
        const int r = slot >> 5, seg = slot & 31;
        const float4* xp = (const float4*)(x + (rowblk + r) * 512 + seg * 16);
        #pragma unroll
        for (int j = 0; j < 4; ++j) v[it*4 + j] = xp[j];
    }
    float bv0[4], bv1[2], bv2v, bvav;
    #pragma unroll
    for (int n = 0; n < 4; ++n) bv0[n] = b0[(wave*4 + n)*16 + (lane & 15)];
    #pragma unroll
    for (int n = 0; n < 2; ++n) bv1[n] = b1[(wave*2 + n)*16 + (lane & 15)];
    bv2v = b2[wave*16 + (lane & 15)];
    bvav = ba[wave*16 + (lane & 15)];

    bf16x8 b0p[2][4];
    #pragma unroll
    for (int p = 0; p < 2; ++p)
        #pragma unroll
        for (int n = 0; n < 4; ++n)
            b0p[p][n] = ldB(W0, wsb, 256, wave*4 + n, p);

    // ---- stage 1: forward 3-level wavelet (thread-local), pack bf16 -> LDS ----
    #pragma unroll
    for (int it = 0; it < 4; ++it) {
        const int slot = tid + it * NT;
        const int r = slot >> 5, seg = slot & 31;
        const float* xa = (const float*)&v[it*4];
        float d0[8], a1[8];
        #pragma unroll
        for (int p = 0; p < 8; ++p) { d0[p] = (xa[2*p] - xa[2*p+1]) * C1f; a1[p] = (xa[2*p] + xa[2*p+1]) * C1f; }
        float d1[4], a2[4];
        #pragma unroll
        for (int p = 0; p < 4; ++p) { d1[p] = (a1[2*p] - a1[2*p+1]) * C1f; a2[p] = (a1[2*p] + a1[2*p+1]) * C1f; }
        float d2[2], a3[2];
        #pragma unroll
        for (int p = 0; p < 2; ++p) { d2[p] = (a2[2*p] - a2[2*p+1]) * C1f; a3[p] = (a2[2*p] + a2[2*p+1]) * C1f; }

        char* rb = lds + r * RB;
        i32x4 pd0 = { (int)pack2(d0[0],d0[1]), (int)pack2(d0[2],d0[3]),
                      (int)pack2(d0[4],d0[5]), (int)pack2(d0[6],d0[7]) };
        *(i32x4*)(rb + seg*16) = pd0;
        u32x2 pd1 = { pack2(d1[0],d1[1]), pack2(d1[2],d1[3]) };
        *(u32x2*)(rb + 512 + seg*8) = pd1;
        *(unsigned int*)(rb + 768 + seg*4) = pack2(d2[0],d2[1]);
        *(unsigned int*)(rb + 896 + seg*4) = pack2(a3[0],a3[1]);
    }
    __syncthreads();   // barrier 1

    // A fragment: lane holds A[m = lane&15][k = (lane>>4)*8 + e]
    auto ldA = [&](int roff, int mtile, int ks) -> bf16x8 {
        const char* p = lds + (mtile*16 + (lane & 15)) * RB + roff + ks*64 + ((lane >> 4) * 16);
        return cast8(*(const i32x4*)p);
    };
    // C store: col = lane&15 (within n-tile), row = (lane>>4)*4 + i
    auto stC = [&](int roff, int mtile, int coloff, f32x4 acc, float bv) {
        const int r0 = mtile*16 + ((lane >> 4) << 2);
        char* base = lds + roff + (coloff + (lane & 15))*2;
        #pragma unroll
        for (int i2 = 0; i2 < 4; ++i2)
            *(unsigned short*)(base + (size_t)(r0 + i2) * RB) = (unsigned short)f2b(acc[i2] + bv);
    };

    // ---- GEMM0: y0[32x256] = d0 @ W0^T  (2-deep B pipeline) ----
    f32x4 acc0[2][4] = {};
    // full prefetch of GEMM1's B (4 ks x 2 n = 32 regs), issued under GEMM0
    bf16x8 b1p[4][2];
    #pragma unroll
    for (int ks = 0; ks < 4; ++ks)
        #pragma unroll
        for (int n = 0; n < 2; ++n)
            b1p[ks][n] = ldB(W1, wsb + 65536, 128, wave*2 + n, ks);

    #pragma unroll
    for (int ks = 0; ks < 8; ++ks) {
        bf16x8 aA = ldA(0, 0, ks);
        bf16x8 aB = ldA(0, 1, ks);
        #pragma unroll
        for (int n = 0; n < 4; ++n) {
            bf16x8 b = b0p[ks & 1][n];
            acc0[0][n] = __builtin_amdgcn_mfma_f32_16x16x32_bf16(aA, b, acc0[0][n], 0, 0, 0);
            acc0[1][n] = __builtin_amdgcn_mfma_f32_16x16x32_bf16(aB, b, acc0[1][n], 0, 0, 0);
            if (ks < 6) b0p[ks & 1][n] = ldB(W0, wsb, 256, wave*4 + n, ks + 2);
        }
    }

    // ---- GEMM1: y1[32x128] = d1 @ W1^T ----
    f32x4 acc1[2][2] = {};
    // prefetch GEMM2/GEMMa B (2 ks x (1+1) = 16 regs) under GEMM1
    bf16x8 b2p[2], bap[2];
    #pragma unroll
    for (int ks = 0; ks < 2; ++ks) {
        b2p[ks] = ldB(W2, wsb + 81920, 64, wave, ks);
        bap[ks] = ldB(Wa, wsb + 86016, 64, wave, ks);
    }
    #pragma unroll
    for (int ks = 0; ks < 4; ++ks) {
        bf16x8 aA = ldA(512, 0, ks);
        bf16x8 aB = ldA(512, 1, ks);
        #pragma unroll
        for (int n = 0; n < 2; ++n) {
            bf16x8 b = b1p[ks][n];
            acc1[0][n] = __builtin_amdgcn_mfma_f32_16x16x32_bf16(aA, b, acc1[0][n], 0, 0, 0);
            acc1[1][n] = __builtin_amdgcn_mfma_f32_16x16x32_bf16(aB, b, acc1[1][n], 0, 0, 0);
        }
    }

    // ---- GEMM2 + GEMMa ----
    f32x4 acc2[2] = {}, acca[2] = {};
    #pragma unroll
    for (int ks = 0; ks < 2; ++ks) {
        bf16x8 aA2 = ldA(768, 0, ks);
        bf16x8 aB2 = ldA(768, 1, ks);
        acc2[0] = __builtin_amdgcn_mfma_f32_16x16x32_bf16(aA2, b2p[ks], acc2[0], 0, 0, 0);
        acc2[1] = __builtin_amdgcn_mfma_f32_16x16x32_bf16(aB2, b2p[ks], acc2[1], 0, 0, 0);
        bf16x8 aAa = ldA(896, 0, ks);
        bf16x8 aBa = ldA(896, 1, ks);
        acca[0] = __builtin_amdgcn_mfma_f32_16x16x32_bf16(aAa, bap[ks], acca[0], 0, 0, 0);
        acca[1] = __builtin_amdgcn_mfma_f32_16x16x32_bf16(aBa, bap[ks], acca[1], 0, 0, 0);
    }

    __syncthreads();   // barrier 2: all LDS A-reads done; safe to overwrite with y

    #pragma unroll
    for (int m = 0; m < 2; ++m) {
        #pragma unroll
        for (int n = 0; n < 4; ++n) stC(0, m, (wave*4 + n)*16, acc0[m][n], bv0[n]);
        #pragma unroll
        for (int n = 0; n < 2; ++n) stC(512, m, (wave*2 + n)*16, acc1[m][n], bv1[n]);
        stC(768, m, wave*16, acc2[m], bv2v);
        stC(896, m, wave*16, acca[m], bvav);
    }
    __syncthreads();   // barrier 3

    // ---- epilogue: inverse wavelet gather + store ----
    #pragma unroll
    for (int it = 0; it < 4; ++it) {
        const int slot = tid + it * NT;
        const int r = slot >> 5, seg = slot & 31;
        const char* yb = lds + r * RB;
        i32x4 p0 = *(const i32x4*)(yb + seg*16);
        u32x2 p1 = *(const u32x2*)(yb + 512 + seg*8);
        unsigned int p2 = *(const unsigned int*)(yb + 768 + seg*4);
        unsigned int pa = *(const unsigned int*)(yb + 896 + seg*4);
        float yd0[8], yd1[4], yd2[2], ya[2];
        #pragma unroll
        for (int i2 = 0; i2 < 4; ++i2) {
            unsigned int w = (unsigned int)p0[i2];
            yd0[2*i2]   = b2f(w & 0xffffu);
            yd0[2*i2+1] = b2f(w >> 16);
        }
        yd1[0] = b2f(p1[0] & 0xffffu); yd1[1] = b2f(p1[0] >> 16);
        yd1[2] = b2f(p1[1] & 0xffffu); yd1[3] = b2f(p1[1] >> 16);
        yd2[0] = b2f(p2 & 0xffffu);    yd2[1] = b2f(p2 >> 16);
        ya[0]  = b2f(pa & 0xffffu);    ya[1]  = b2f(pa >> 16);

        float o[16];
        #pragma unroll
        for (int jj = 0; jj < 16; ++jj) {
            const float s0 = (jj & 1)        ? -C1f : C1f;
            const float s1 = ((jj >> 1) & 1) ? -C2f : C2f;
            const float s2 = ((jj >> 2) & 1) ? -C3f : C3f;
            o[jj] = C3f * ya[jj >> 3] + s2 * yd2[jj >> 3] + s1 * yd1[jj >> 2] + s0 * yd0[jj >> 1];
        }
        float4* op = (float4*)(out + (rowblk + r) * 512 + seg * 16);
        const float4* ov = (const float4*)o;
        op[0] = ov[0]; op[1] = ov[1]; op[2] = ov[2]; op[3] = ov[3];
    }
}

// convert all weights to bf16 into workspace (runs every call; deterministic)
__global__ void conv_weights(const float* __restrict__ W0, const float* __restrict__ W1,
                             const float* __restrict__ W2, const float* __restrict__ Wa,
                             unsigned short* __restrict__ ws)
{
    const int i = blockIdx.x * 256 + threadIdx.x;
    if (i < 65536)        ws[i] = (unsigned short)f2b(W0[i]);
    else if (i < 81920)   ws[i] = (unsigned short)f2b(W1[i - 65536]);
    else if (i < 86016)   ws[i] = (unsigned short)f2b(W2[i - 81920]);
    else if (i < 90112)   ws[i] = (unsigned short)f2b(Wa[i - 86016]);
}

extern "C" void kernel_launch(void* const* d_in, const int* in_sizes, int n_in,
                              void* d_out, int out_size, void* d_ws, size_t ws_size,
                              hipStream_t stream)
{
    const float* x  = (const float*)d_in[0];
    const float* W0 = (const float*)d_in[1];
    const float* b0 = (const float*)d_in[2];
    const float* W1 = (const float*)d_in[3];
    const float* b1 = (const float*)d_in[4];
    const float* W2 = (const float*)d_in[5];
    const float* b2 = (const float*)d_in[6];
    const float* Wa = (const float*)d_in[7];
    const float* ba = (const float*)d_in[8];
    float* out = (float*)d_out;

    const int nrows = in_sizes[0] / 512;      // 65536
    const int nblk  = nrows / RPB;            // 2048

    if (ws_size >= (size_t)90112 * sizeof(unsigned short)) {
        unsigned short* ws = (unsigned short*)d_ws;
        conv_weights<<<352, 256, 0, stream>>>(W0, W1, W2, Wa, ws);
        wavelet_mlp<1><<<nblk, NT, 0, stream>>>(x, W0, b0, W1, b1, W2, b2, Wa, ba, ws, out);
    } else {
        wavelet_mlp<0><<<nblk, NT, 0, stream>>>(x, W0, b0, W1, b1, W2, b2, Wa, ba, nullptr, out);
    }
}